// Round 1
// baseline (697.116 us; speedup 1.0000x reference)
//
#include <hip/hip_runtime.h>
#include <hip/hip_bf16.h>

// Problem constants
#define NN0 4096
#define NEDGE 131072
#define NMP 3

typedef __attribute__((ext_vector_type(8))) short bf16x8;
typedef __attribute__((ext_vector_type(4))) float f32x4;

__device__ __forceinline__ unsigned short f2b(float v) {
  __hip_bfloat16 h = __float2bfloat16(v);
  return __builtin_bit_cast(unsigned short, h);
}

__device__ __forceinline__ void gload_lds16(const void* g, void* l) {
  __builtin_amdgcn_global_load_lds(
      (const __attribute__((address_space(1))) void*)g,
      (__attribute__((address_space(3))) void*)l, 16, 0, 0);
}

#define MFMA(a, b, c) __builtin_amdgcn_mfma_f32_16x16x32_bf16((a), (b), (c), 0, 0, 0)

// ---------------- weight prep: f32 [K][C] -> bf16 MFMA-B-fragment layout ----------------
// out[((ct*nkt + kt)*64 + lane)*8 + j] = W[kt*32 + (lane>>4)*8 + j][ct*16 + (lane&15)]
__global__ void wfrag_kernel(const float* __restrict__ src, unsigned short* __restrict__ dst,
                             int K, int C, int lgnkt) {
  int t = blockIdx.x * 256 + threadIdx.x;
  if (t >= K * C) return;
  const int j = t & 7;
  const int l = (t >> 3) & 63;
  const int rest = t >> 9;
  const int kt = rest & ((1 << lgnkt) - 1);
  const int ct = rest >> lgnkt;
  const int r = l & 15, q = l >> 4;
  const int k = (kt << 5) + (q << 3) + j;
  const int c = (ct << 4) + r;
  dst[t] = f2b(src[k * C + c]);
}

__global__ void nodeconv_kernel(const float* __restrict__ n0, const float* __restrict__ n1,
                                unsigned short* __restrict__ n0b, float* __restrict__ n0f,
                                unsigned short* __restrict__ n1b) {
  const int t = blockIdx.x * 256 + threadIdx.x;
  const float a = n0[t], b = n1[t];
  n0b[t] = f2b(a);
  n0f[t] = a;
  n1b[t] = f2b(b);
}

// ---------------- edge MLP: gather -> 3-layer MLP -> atomic scatter ----------------
__global__ __launch_bounds__(256, 2) void edge_mlp_kernel(
    const unsigned short* __restrict__ n0b, const unsigned short* __restrict__ n1b,
    const int* __restrict__ rowi, const int* __restrict__ coli,
    const unsigned short* __restrict__ W1, const float* __restrict__ b1,
    const unsigned short* __restrict__ W2, const float* __restrict__ b2,
    const float* __restrict__ lng, const float* __restrict__ lnb,
    const unsigned short* __restrict__ W3, const float* __restrict__ b3,
    float* __restrict__ agg)
{
  __shared__ unsigned short smem[64 * 512];            // 64KB: A-tile; lower 32KB reused as H-tile
  float* lnp = (float*)((char*)smem + 32768);          // 2KB overlay on dead upper A-tile

  const int tid = (int)threadIdx.x;
  const int w = tid >> 6, l = tid & 63, r = l & 15, q = l >> 4;
  const int e0 = (int)blockIdx.x * 64;
  const int c0 = w << 6;
  const int swz = (r & 7) << 4;

  // stage 64 gathered rows [64][512] bf16; source-lane permuted for XOR swizzle
  #pragma unroll
  for (int ar = 0; ar < 16; ++ar) {
    const int arow = (w << 4) + ar;
    const int e = e0 + arow;
    const int ridx = rowi[e], cidx = coli[e];
    const int sc = l ^ (arow & 7);
    const unsigned short* gp = (sc < 32) ? (n0b + ridx * 256 + sc * 8)
                                         : (n1b + cidx * 256 + (sc - 32) * 8);
    gload_lds16(gp, &smem[arow * 512]);
  }
  __syncthreads();

  // GEMM1: [64,512] @ [512,256], wave owns cols [c0, c0+64)
  f32x4 acc[4][4];
  #pragma unroll
  for (int mt = 0; mt < 4; ++mt)
    #pragma unroll
    for (int nt = 0; nt < 4; ++nt)
      acc[mt][nt] = f32x4{0.f, 0.f, 0.f, 0.f};

  for (int ks = 0; ks < 16; ++ks) {
    bf16x8 a[4];
    #pragma unroll
    for (int mt = 0; mt < 4; ++mt)
      a[mt] = *(const bf16x8*)((const char*)smem + ((mt << 4) + r) * 1024 +
                               (((ks << 6) | (q << 4)) ^ swz));
    #pragma unroll
    for (int nt = 0; nt < 4; ++nt) {
      bf16x8 b = *(const bf16x8*)(W1 + ((((w << 2) + nt) << 4) + ks) * 512 + (l << 3));
      #pragma unroll
      for (int mt = 0; mt < 4; ++mt)
        acc[mt][nt] = MFMA(a[mt], b, acc[mt][nt]);
    }
  }
  #pragma unroll
  for (int nt = 0; nt < 4; ++nt) {
    const float bias = b1[c0 + (nt << 4) + r];
    #pragma unroll
    for (int mt = 0; mt < 4; ++mt)
      #pragma unroll
      for (int i = 0; i < 4; ++i)
        acc[mt][nt][i] = fmaxf(acc[mt][nt][i] + bias, 0.f);
  }
  __syncthreads();                                     // all waves done reading A-tile
  #pragma unroll
  for (int mt = 0; mt < 4; ++mt)
    #pragma unroll
    for (int i = 0; i < 4; ++i) {
      const int hr = (mt << 4) + (q << 2) + i;
      const int hswz = (hr & 7) << 4;
      #pragma unroll
      for (int nt = 0; nt < 4; ++nt) {
        const int hc = c0 + (nt << 4) + r;
        *(unsigned short*)((char*)smem + hr * 512 + ((hc * 2) ^ hswz)) = f2b(acc[mt][nt][i]);
      }
    }
  __syncthreads();

  // GEMM2: [64,256] @ [256,256]
  f32x4 acc2[4][4];
  #pragma unroll
  for (int mt = 0; mt < 4; ++mt)
    #pragma unroll
    for (int nt = 0; nt < 4; ++nt)
      acc2[mt][nt] = f32x4{0.f, 0.f, 0.f, 0.f};

  for (int ks = 0; ks < 8; ++ks) {
    bf16x8 a[4];
    #pragma unroll
    for (int mt = 0; mt < 4; ++mt)
      a[mt] = *(const bf16x8*)((const char*)smem + ((mt << 4) + r) * 512 +
                               (((ks << 6) | (q << 4)) ^ swz));
    #pragma unroll
    for (int nt = 0; nt < 4; ++nt) {
      bf16x8 b = *(const bf16x8*)(W2 + ((((w << 2) + nt) << 3) + ks) * 512 + (l << 3));
      #pragma unroll
      for (int mt = 0; mt < 4; ++mt)
        acc2[mt][nt] = MFMA(a[mt], b, acc2[mt][nt]);
    }
  }
  #pragma unroll
  for (int nt = 0; nt < 4; ++nt) {
    const float bias = b2[c0 + (nt << 4) + r];
    #pragma unroll
    for (int mt = 0; mt < 4; ++mt)
      #pragma unroll
      for (int i = 0; i < 4; ++i)
        acc2[mt][nt][i] += bias;
  }
  // LayerNorm stats: per-row mean/var over 256 cols (butterfly within q-group, LDS across waves)
  #pragma unroll
  for (int mt = 0; mt < 4; ++mt)
    #pragma unroll
    for (int i = 0; i < 4; ++i) {
      float s = 0.f, s2 = 0.f;
      #pragma unroll
      for (int nt = 0; nt < 4; ++nt) { const float x = acc2[mt][nt][i]; s += x; s2 += x * x; }
      #pragma unroll
      for (int m = 1; m < 16; m <<= 1) { s += __shfl_xor(s, m, 64); s2 += __shfl_xor(s2, m, 64); }
      if (r == 0) {
        const int rr = (mt << 4) + (q << 2) + i;
        lnp[(w << 6) + rr] = s;
        lnp[256 + (w << 6) + rr] = s2;
      }
    }
  __syncthreads();
  float mu[4][4], rstd[4][4];
  #pragma unroll
  for (int mt = 0; mt < 4; ++mt)
    #pragma unroll
    for (int i = 0; i < 4; ++i) {
      const int rr = (mt << 4) + (q << 2) + i;
      const float s  = lnp[rr] + lnp[64 + rr] + lnp[128 + rr] + lnp[192 + rr];
      const float s2 = lnp[256 + rr] + lnp[256 + 64 + rr] + lnp[256 + 128 + rr] + lnp[256 + 192 + rr];
      const float mean = s * (1.f / 256.f);
      const float var = s2 * (1.f / 256.f) - mean * mean;
      mu[mt][i] = mean;
      rstd[mt][i] = rsqrtf(var + 1e-5f);
    }
  // normalize * g + b, relu, write h2 to H-tile
  #pragma unroll
  for (int nt = 0; nt < 4; ++nt) {
    const int hc = c0 + (nt << 4) + r;
    const float gv = lng[hc], bv = lnb[hc];
    #pragma unroll
    for (int mt = 0; mt < 4; ++mt)
      #pragma unroll
      for (int i = 0; i < 4; ++i) {
        const int hr = (mt << 4) + (q << 2) + i;
        const float x = fmaxf((acc2[mt][nt][i] - mu[mt][i]) * rstd[mt][i] * gv + bv, 0.f);
        *(unsigned short*)((char*)smem + hr * 512 + ((hc * 2) ^ ((hr & 7) << 4))) = f2b(x);
      }
  }
  __syncthreads();

  // GEMM3: [64,256] @ [256,256]
  f32x4 acc3[4][4];
  #pragma unroll
  for (int mt = 0; mt < 4; ++mt)
    #pragma unroll
    for (int nt = 0; nt < 4; ++nt)
      acc3[mt][nt] = f32x4{0.f, 0.f, 0.f, 0.f};

  for (int ks = 0; ks < 8; ++ks) {
    bf16x8 a[4];
    #pragma unroll
    for (int mt = 0; mt < 4; ++mt)
      a[mt] = *(const bf16x8*)((const char*)smem + ((mt << 4) + r) * 512 +
                               (((ks << 6) | (q << 4)) ^ swz));
    #pragma unroll
    for (int nt = 0; nt < 4; ++nt) {
      bf16x8 b = *(const bf16x8*)(W3 + ((((w << 2) + nt) << 3) + ks) * 512 + (l << 3));
      #pragma unroll
      for (int mt = 0; mt < 4; ++mt)
        acc3[mt][nt] = MFMA(a[mt], b, acc3[mt][nt]);
    }
  }
  float bias3[4];
  #pragma unroll
  for (int nt = 0; nt < 4; ++nt) bias3[nt] = b3[c0 + (nt << 4) + r];
  // scatter-add into agg
  #pragma unroll
  for (int mt = 0; mt < 4; ++mt)
    #pragma unroll
    for (int i = 0; i < 4; ++i) {
      const int e = e0 + (mt << 4) + (q << 2) + i;
      float* dst = agg + rowi[e] * 256 + c0 + r;
      #pragma unroll
      for (int nt = 0; nt < 4; ++nt)
        atomicAdd(dst + (nt << 4), acc3[mt][nt][i] + bias3[nt]);
    }
}

// ---------------- node MLP: [16 rows/block] concat(node0, agg) -> MLP -> +residual ----------------
__global__ __launch_bounds__(256, 2) void node_mlp_kernel(
    const float* __restrict__ n0f, const float* __restrict__ agg,
    const unsigned short* __restrict__ W1, const float* __restrict__ b1,
    const unsigned short* __restrict__ W2, const float* __restrict__ b2,
    const float* __restrict__ lng, const float* __restrict__ lnb,
    const unsigned short* __restrict__ W3, const float* __restrict__ b3,
    float* __restrict__ outf, unsigned short* __restrict__ outb)
{
  __shared__ unsigned short smem[16 * 512];            // 16KB
  float* lnp = (float*)((char*)smem + 8192);           // overlay on dead upper A-tile
  const int tid = (int)threadIdx.x;
  const int w = tid >> 6, l = tid & 63, r = l & 15, q = l >> 4;
  const int r0 = (int)blockIdx.x << 4;
  const int c0 = w << 6;
  const int swz = (r & 7) << 4;

  #pragma unroll
  for (int ar = 0; ar < 4; ++ar) {
    const int arow = (w << 2) + ar;
    const int nrow = r0 + arow;
    const float* src = (l < 32) ? (n0f + nrow * 256 + (l << 3))
                                : (agg + nrow * 256 + ((l - 32) << 3));
    const f32x4 x0 = *(const f32x4*)src;
    const f32x4 x1 = *(const f32x4*)(src + 4);
    bf16x8 pk;
    pk[0] = (short)f2b(x0[0]); pk[1] = (short)f2b(x0[1]);
    pk[2] = (short)f2b(x0[2]); pk[3] = (short)f2b(x0[3]);
    pk[4] = (short)f2b(x1[0]); pk[5] = (short)f2b(x1[1]);
    pk[6] = (short)f2b(x1[2]); pk[7] = (short)f2b(x1[3]);
    *(bf16x8*)((char*)smem + arow * 1024 + ((l << 4) ^ ((arow & 7) << 4))) = pk;
  }
  __syncthreads();

  f32x4 acc[4];
  #pragma unroll
  for (int nt = 0; nt < 4; ++nt) acc[nt] = f32x4{0.f, 0.f, 0.f, 0.f};
  for (int ks = 0; ks < 16; ++ks) {
    bf16x8 a = *(const bf16x8*)((const char*)smem + r * 1024 + (((ks << 6) | (q << 4)) ^ swz));
    #pragma unroll
    for (int nt = 0; nt < 4; ++nt) {
      bf16x8 b = *(const bf16x8*)(W1 + ((((w << 2) + nt) << 4) + ks) * 512 + (l << 3));
      acc[nt] = MFMA(a, b, acc[nt]);
    }
  }
  #pragma unroll
  for (int nt = 0; nt < 4; ++nt) {
    const float bias = b1[c0 + (nt << 4) + r];
    #pragma unroll
    for (int i = 0; i < 4; ++i) acc[nt][i] = fmaxf(acc[nt][i] + bias, 0.f);
  }
  __syncthreads();
  #pragma unroll
  for (int i = 0; i < 4; ++i) {
    const int hr = (q << 2) + i;
    const int hswz = (hr & 7) << 4;
    #pragma unroll
    for (int nt = 0; nt < 4; ++nt) {
      const int hc = c0 + (nt << 4) + r;
      *(unsigned short*)((char*)smem + hr * 512 + ((hc * 2) ^ hswz)) = f2b(acc[nt][i]);
    }
  }
  __syncthreads();

  f32x4 acc2[4];
  #pragma unroll
  for (int nt = 0; nt < 4; ++nt) acc2[nt] = f32x4{0.f, 0.f, 0.f, 0.f};
  for (int ks = 0; ks < 8; ++ks) {
    bf16x8 a = *(const bf16x8*)((const char*)smem + r * 512 + (((ks << 6) | (q << 4)) ^ swz));
    #pragma unroll
    for (int nt = 0; nt < 4; ++nt) {
      bf16x8 b = *(const bf16x8*)(W2 + ((((w << 2) + nt) << 3) + ks) * 512 + (l << 3));
      acc2[nt] = MFMA(a, b, acc2[nt]);
    }
  }
  #pragma unroll
  for (int nt = 0; nt < 4; ++nt) {
    const float bias = b2[c0 + (nt << 4) + r];
    #pragma unroll
    for (int i = 0; i < 4; ++i) acc2[nt][i] += bias;
  }
  #pragma unroll
  for (int i = 0; i < 4; ++i) {
    float s = 0.f, s2 = 0.f;
    #pragma unroll
    for (int nt = 0; nt < 4; ++nt) { const float x = acc2[nt][i]; s += x; s2 += x * x; }
    #pragma unroll
    for (int m = 1; m < 16; m <<= 1) { s += __shfl_xor(s, m, 64); s2 += __shfl_xor(s2, m, 64); }
    if (r == 0) {
      const int rr = (q << 2) + i;
      lnp[(w << 4) + rr] = s;
      lnp[64 + (w << 4) + rr] = s2;
    }
  }
  __syncthreads();
  float mu[4], rstd[4];
  #pragma unroll
  for (int i = 0; i < 4; ++i) {
    const int rr = (q << 2) + i;
    const float s  = lnp[rr] + lnp[16 + rr] + lnp[32 + rr] + lnp[48 + rr];
    const float s2 = lnp[64 + rr] + lnp[80 + rr] + lnp[96 + rr] + lnp[112 + rr];
    const float mean = s * (1.f / 256.f);
    const float var = s2 * (1.f / 256.f) - mean * mean;
    mu[i] = mean;
    rstd[i] = rsqrtf(var + 1e-5f);
  }
  #pragma unroll
  for (int nt = 0; nt < 4; ++nt) {
    const int hc = c0 + (nt << 4) + r;
    const float gv = lng[hc], bv = lnb[hc];
    #pragma unroll
    for (int i = 0; i < 4; ++i) {
      const int hr = (q << 2) + i;
      const float x = fmaxf((acc2[nt][i] - mu[i]) * rstd[i] * gv + bv, 0.f);
      *(unsigned short*)((char*)smem + hr * 512 + ((hc * 2) ^ ((hr & 7) << 4))) = f2b(x);
    }
  }
  __syncthreads();

  f32x4 acc3[4];
  #pragma unroll
  for (int nt = 0; nt < 4; ++nt) acc3[nt] = f32x4{0.f, 0.f, 0.f, 0.f};
  for (int ks = 0; ks < 8; ++ks) {
    bf16x8 a = *(const bf16x8*)((const char*)smem + r * 512 + (((ks << 6) | (q << 4)) ^ swz));
    #pragma unroll
    for (int nt = 0; nt < 4; ++nt) {
      bf16x8 b = *(const bf16x8*)(W3 + ((((w << 2) + nt) << 3) + ks) * 512 + (l << 3));
      acc3[nt] = MFMA(a, b, acc3[nt]);
    }
  }
  float bias3[4];
  #pragma unroll
  for (int nt = 0; nt < 4; ++nt) bias3[nt] = b3[c0 + (nt << 4) + r];
  #pragma unroll
  for (int i = 0; i < 4; ++i) {
    const int nrow = r0 + (q << 2) + i;
    #pragma unroll
    for (int nt = 0; nt < 4; ++nt) {
      const int col = c0 + (nt << 4) + r;
      const float y = acc3[nt][i] + bias3[nt] + n0f[nrow * 256 + col];
      outf[nrow * 256 + col] = y;
      outb[nrow * 256 + col] = f2b(y);
    }
  }
}

// ---------------- edge predictor: gather -> Linear+ReLU -> dot -> sigmoid ----------------
__global__ __launch_bounds__(256, 2) void pred_kernel(
    const unsigned short* __restrict__ n0b, const unsigned short* __restrict__ n1b,
    const int* __restrict__ rowi, const int* __restrict__ coli,
    const unsigned short* __restrict__ W1, const float* __restrict__ b1,
    const float* __restrict__ w2, const float* __restrict__ b2,
    float* __restrict__ out)
{
  __shared__ unsigned short smem[64 * 512];
  float* part = (float*)((char*)smem + 32768);

  const int tid = (int)threadIdx.x;
  const int w = tid >> 6, l = tid & 63, r = l & 15, q = l >> 4;
  const int e0 = (int)blockIdx.x * 64;
  const int c0 = w << 6;
  const int swz = (r & 7) << 4;

  #pragma unroll
  for (int ar = 0; ar < 16; ++ar) {
    const int arow = (w << 4) + ar;
    const int e = e0 + arow;
    const int ridx = rowi[e], cidx = coli[e];
    const int sc = l ^ (arow & 7);
    const unsigned short* gp = (sc < 32) ? (n0b + ridx * 256 + sc * 8)
                                         : (n1b + cidx * 256 + (sc - 32) * 8);
    gload_lds16(gp, &smem[arow * 512]);
  }
  __syncthreads();

  f32x4 acc[4][4];
  #pragma unroll
  for (int mt = 0; mt < 4; ++mt)
    #pragma unroll
    for (int nt = 0; nt < 4; ++nt)
      acc[mt][nt] = f32x4{0.f, 0.f, 0.f, 0.f};

  for (int ks = 0; ks < 16; ++ks) {
    bf16x8 a[4];
    #pragma unroll
    for (int mt = 0; mt < 4; ++mt)
      a[mt] = *(const bf16x8*)((const char*)smem + ((mt << 4) + r) * 1024 +
                               (((ks << 6) | (q << 4)) ^ swz));
    #pragma unroll
    for (int nt = 0; nt < 4; ++nt) {
      bf16x8 b = *(const bf16x8*)(W1 + ((((w << 2) + nt) << 4) + ks) * 512 + (l << 3));
      #pragma unroll
      for (int mt = 0; mt < 4; ++mt)
        acc[mt][nt] = MFMA(a[mt], b, acc[mt][nt]);
    }
  }
  float wv[4];
  #pragma unroll
  for (int nt = 0; nt < 4; ++nt) wv[nt] = w2[c0 + (nt << 4) + r];
  #pragma unroll
  for (int nt = 0; nt < 4; ++nt) {
    const float bias = b1[c0 + (nt << 4) + r];
    #pragma unroll
    for (int mt = 0; mt < 4; ++mt)
      #pragma unroll
      for (int i = 0; i < 4; ++i)
        acc[mt][nt][i] = fmaxf(acc[mt][nt][i] + bias, 0.f);
  }
  __syncthreads();                                     // A-tile (incl. part region) now dead
  #pragma unroll
  for (int mt = 0; mt < 4; ++mt)
    #pragma unroll
    for (int i = 0; i < 4; ++i) {
      float s = 0.f;
      #pragma unroll
      for (int nt = 0; nt < 4; ++nt) s += acc[mt][nt][i] * wv[nt];
      #pragma unroll
      for (int m = 1; m < 16; m <<= 1) s += __shfl_xor(s, m, 64);
      if (r == 0) part[(w << 6) + (mt << 4) + (q << 2) + i] = s;
    }
  __syncthreads();
  if (tid < 64) {
    const float s = part[tid] + part[64 + tid] + part[128 + tid] + part[192 + tid] + b2[0];
    out[e0 + tid] = 1.f / (1.f + expf(-s));
  }
}

// ---------------- launch ----------------
extern "C" void kernel_launch(void* const* d_in, const int* in_sizes, int n_in,
                              void* d_out, int out_size, void* d_ws, size_t ws_size,
                              hipStream_t stream) {
  const float* node0 = (const float*)d_in[0];
  const float* node1 = (const float*)d_in[1];
  const int* rowi = (const int*)d_in[2];
  const int* coli = (const int*)d_in[3];
  const float* e_w1 = (const float*)d_in[4];
  const float* e_b1 = (const float*)d_in[5];
  const float* e_w2 = (const float*)d_in[6];
  const float* e_b2 = (const float*)d_in[7];
  const float* e_g  = (const float*)d_in[8];
  const float* e_be = (const float*)d_in[9];
  const float* e_w3 = (const float*)d_in[10];
  const float* e_b3 = (const float*)d_in[11];
  const float* n_w1 = (const float*)d_in[12];
  const float* n_b1 = (const float*)d_in[13];
  const float* n_w2 = (const float*)d_in[14];
  const float* n_b2 = (const float*)d_in[15];
  const float* n_g  = (const float*)d_in[16];
  const float* n_be = (const float*)d_in[17];
  const float* n_w3 = (const float*)d_in[18];
  const float* n_b3 = (const float*)d_in[19];
  const float* p_w1 = (const float*)d_in[20];
  const float* p_b1 = (const float*)d_in[21];
  const float* p_w2 = (const float*)d_in[22];
  const float* p_b2 = (const float*)d_in[23];

  char* ws = (char*)d_ws;
  unsigned short* WTe1 = (unsigned short*)(ws + 0);         // 512x256 bf16  (262144 B)
  unsigned short* WTe2 = (unsigned short*)(ws + 262144);    // 256x256
  unsigned short* WTe3 = (unsigned short*)(ws + 393216);
  unsigned short* WTn1 = (unsigned short*)(ws + 524288);
  unsigned short* WTn2 = (unsigned short*)(ws + 786432);
  unsigned short* WTn3 = (unsigned short*)(ws + 917504);
  unsigned short* WTp1 = (unsigned short*)(ws + 1048576);
  unsigned short* n1b  = (unsigned short*)(ws + 1310720);   // 2MB
  unsigned short* n0bA = (unsigned short*)(ws + 3407872);   // 2MB
  unsigned short* n0bB = (unsigned short*)(ws + 5505024);   // 2MB
  float* n0fA = (float*)(ws + 7602176);                     // 4MB
  float* n0fB = (float*)(ws + 11796480);                    // 4MB
  float* agg  = (float*)(ws + 15990784);                    // 4MB

  wfrag_kernel<<<512, 256, 0, stream>>>(e_w1, WTe1, 512, 256, 4);
  wfrag_kernel<<<256, 256, 0, stream>>>(e_w2, WTe2, 256, 256, 3);
  wfrag_kernel<<<256, 256, 0, stream>>>(e_w3, WTe3, 256, 256, 3);
  wfrag_kernel<<<512, 256, 0, stream>>>(n_w1, WTn1, 512, 256, 4);
  wfrag_kernel<<<256, 256, 0, stream>>>(n_w2, WTn2, 256, 256, 3);
  wfrag_kernel<<<256, 256, 0, stream>>>(n_w3, WTn3, 256, 256, 3);
  wfrag_kernel<<<512, 256, 0, stream>>>(p_w1, WTp1, 512, 256, 4);
  nodeconv_kernel<<<4096, 256, 0, stream>>>(node0, node1, n0bA, n0fA, n1b);

  const unsigned short* curb = n0bA; unsigned short* nxtb = n0bB;
  const float* curf = n0fA; float* nxtf = n0fB;
  for (int it = 0; it < NMP; ++it) {
    hipMemsetAsync(agg, 0, (size_t)NN0 * 256 * 4, stream);
    edge_mlp_kernel<<<NEDGE / 64, 256, 0, stream>>>(curb, n1b, rowi, coli,
        WTe1, e_b1, WTe2, e_b2, e_g, e_be, WTe3, e_b3, agg);
    node_mlp_kernel<<<NN0 / 16, 256, 0, stream>>>(curf, agg,
        WTn1, n_b1, WTn2, n_b2, n_g, n_be, WTn3, n_b3, nxtf, nxtb);
    const unsigned short* tb = curb; curb = nxtb; nxtb = (unsigned short*)tb;
    const float* tf = curf; curf = nxtf; nxtf = (float*)tf;
  }
  pred_kernel<<<NEDGE / 64, 256, 0, stream>>>(curb, n1b, rowi, coli,
      WTp1, p_b1, p_w2, p_b2, (float*)d_out);
}